// Round 1
// 347.718 us; speedup vs baseline: 1.0049x; 1.0049x over previous
//
#include <hip/hip_runtime.h>

// metaCLF: per-voxel MLP filter gen + filtering. MFMA, barrier-free.
// x: [2,32,96^3] f32, d_all: [2,6,96^3] f32
// W1:[16,2] W2:[3,16] G1:[32,27] G2:[64,32] G3:[32,64] -> out: [2,1,96^3] f32
//
// Round 7 (from R6, metaclf dispatch ~80us vs 44us HBM floor): the x stream
// (226 MB = 82% of all traffic) was loaded in phase 5, AFTER three
// LDS_FENCE()s whose "memory" clobber pins the 32 global loads behind all
// compute -> full ~900-cyc HBM latency exposed at the wave tail, with all 4
// resident waves/SIMD arriving there in lockstep. Fix: prefetch x into 32
// VGPRs issued at the END of phase 1 (after d_all is consumed, so the
// compiler's vmcnt wait for d_all doesn't drain the x queue; before the
// first fence, so the clobber pins the issue point). HBM service overlaps
// phases 2-4. Also: phase-5 dot split into 4 accumulator chains (was one
// 32-deep fma chain). __launch_bounds__(256,4) pins VGPR<=128 so the
// LDS-bound 4 blocks/CU occupancy can't silently drop.
// Everything else per R6: wave-private 64 voxels, no barriers (DS in-order
// within wave), single in-place LDS buffer (stride 72 f16), weights
// prepacked to d_ws, activations scaled 2^14 (relu pos-homogeneous),
// MFMA operand order D = W * Act (thread's 4 acc elems = 4 contiguous
// channels of one voxel -> b64/b128 DS stores).

typedef _Float16 f16x8 __attribute__((ext_vector_type(8)));
typedef _Float16 f16x4 __attribute__((ext_vector_type(4)));
typedef float    f32x4 __attribute__((ext_vector_type(4)));

constexpr int V3   = 96 * 96 * 96;   // 884736
constexpr int NVOX = 2 * V3;         // 1769472
constexpr int TV   = 256;            // voxels per block
constexpr int NBLK = NVOX / TV;      // 6912
constexpr int S    = 72;             // LDS row stride, f16 units (144 B)
constexpr int SD   = 36;             // same stride in f32 units

constexpr float SCALE     = 16384.f;
constexpr float INV_SCALE = 1.f / 16384.f;

// ws fragment table: 10 tiles x 64 lanes x 8 f16 = 10240 B
// tiles: 0,1 = G1 (m-half) ; 2..5 = G2 (m-quarter q) ; 6..9 = G3 (kh*2+mh)
constexpr int N_TILES  = 10;
constexpr int WS_BYTES = N_TILES * 64 * 8 * 2;

#define LDS_FENCE() asm volatile("s_waitcnt lgkmcnt(0)" ::: "memory")

__device__ __forceinline__ f16x8 build_frag(int tile, int n16, int quad,
                                            const float* __restrict__ G1,
                                            const float* __restrict__ G2,
                                            const float* __restrict__ G3) {
    f16x8 v;
    const int k0 = quad * 8;
#pragma unroll
    for (int j = 0; j < 8; ++j) {
        float f = 0.f;
        const int k = k0 + j;
        if (tile < 2) {
            if (k < 27) f = G1[(tile * 16 + n16) * 27 + k];
        } else if (tile < 6) {
            f = G2[((tile - 2) * 16 + n16) * 32 + k];
        } else {
            const int kh = (tile - 6) >> 1, nh = (tile - 6) & 1;
            f = G3[(nh * 16 + n16) * 64 + kh * 32 + k];
        }
        v[j] = (_Float16)f;
    }
    return v;
}

__global__ __launch_bounds__(256) void pack_weights(
    const float* __restrict__ G1, const float* __restrict__ G2,
    const float* __restrict__ G3, _Float16* __restrict__ wf)
{
    for (int slot = threadIdx.x; slot < N_TILES * 64; slot += 256) {
        const int tile = slot >> 6;
        const int lane = slot & 63;
        const f16x8 v = build_frag(tile, lane & 15, lane >> 4, G1, G2, G3);
        *(f16x8*)&wf[slot * 8] = v;
    }
}

template <bool USE_WS>
__global__ __launch_bounds__(256, 4) void metaclf_mfma3(
    const float* __restrict__ x,
    const float* __restrict__ d_all,
    const float* __restrict__ W1,
    const float* __restrict__ W2,
    const float* __restrict__ G1,
    const float* __restrict__ G2,
    const float* __restrict__ G3,
    const _Float16* __restrict__ wf,
    float* __restrict__ out)
{
    __shared__ _Float16 lds[TV * S];           // 36,864 B
    float* const ldsf = (float*)lds;

    const int t    = threadIdx.x;
    const int lane = t & 63;
    const int wave = t >> 6;
    const int n16  = lane & 15;
    const int quad = lane >> 4;
    const int g0   = wave * 4;                 // first 16-voxel group of this wave

    const int gidx = blockIdx.x * TV + t;
    const int b = (gidx >= V3) ? 1 : 0;        // uniform per block
    const int v = gidx - b * V3;

    auto frag = [&](int tile) -> f16x8 {
        if constexpr (USE_WS) return *(const f16x8*)&wf[(tile * 64 + lane) * 8];
        else                  return build_frag(tile, n16, quad, G1, G2, G3);
    };

    float xv[32];                              // prefetched x (issued end of phase 1)

    // ========== Phase 1: encode + kron (fp32, exact), scaled -> E (f16) ==========
    {
        float e[3][3];
#pragma unroll
        for (int a = 0; a < 3; ++a) {
            const float d0 = d_all[(b * 6 + 2 * a    ) * V3 + v];
            const float d1 = d_all[(b * 6 + 2 * a + 1) * V3 + v];
            float a0 = 0.f, a1 = 0.f, a2 = 0.f;
#pragma unroll
            for (int k = 0; k < 16; ++k) {
                const float tt = fmaxf(fmaf(W1[k * 2], d0, W1[k * 2 + 1] * d1), 0.f);
                a0 = fmaf(W2[0 * 16 + k], tt, a0);
                a1 = fmaf(W2[1 * 16 + k], tt, a1);
                a2 = fmaf(W2[2 * 16 + k], tt, a2);
            }
            e[a][0] = a0; e[a][1] = a1; e[a][2] = a2;
        }
        _Float16 row[32];
#pragma unroll
        for (int i = 0; i < 3; ++i)
#pragma unroll
            for (int j = 0; j < 3; ++j) {
                const float p = e[0][i] * e[1][j] * SCALE;
#pragma unroll
                for (int k = 0; k < 3; ++k)
                    row[i * 9 + j * 3 + k] = (_Float16)(p * e[2][k]);
            }
#pragma unroll
        for (int m = 27; m < 32; ++m) row[m] = (_Float16)0.f;

        f16x8* dst = (f16x8*)&lds[t * S];
#pragma unroll
        for (int i = 0; i < 4; ++i) dst[i] = ((const f16x8*)row)[i];
    }

    // ---- x prefetch: issue ALL 32 channel loads NOW. d_all is already
    // consumed (its vmcnt wait is behind us), so these 32 loads stay in
    // flight across phases 2-4; the fence clobbers below pin the issue
    // point and forbid sinking them back into phase 5. ----
    {
        const float* xb = x + (size_t)(b * 32) * V3 + v;
#pragma unroll
        for (int i = 0; i < 32; ++i) xv[i] = xb[(size_t)i * V3];
    }

    LDS_FENCE();   // wave-local: own 64 rows fully written

    // ========== Phase 2: G1 (27->32), E -> H1, in place ==========
    // D = G1 * E^T : m = out-channel, n = voxel. Thread stores channels
    // [quad*4, quad*4+4) and [16+quad*4, ...) of voxel rowv+n16 as b64.
    {
        const f16x8 b0 = frag(0);
        const f16x8 b1 = frag(1);
#pragma unroll
        for (int g = 0; g < 4; ++g) {
            const int rowv = (g0 + g) * 16;
            const f16x8 a = *(const f16x8*)&lds[(rowv + n16) * S + quad * 8];
            f32x4 c0 = {0.f, 0.f, 0.f, 0.f}, c1 = {0.f, 0.f, 0.f, 0.f};
            c0 = __builtin_amdgcn_mfma_f32_16x16x32_f16(b0, a, c0, 0, 0, 0);
            c1 = __builtin_amdgcn_mfma_f32_16x16x32_f16(b1, a, c1, 0, 0, 0);
            f16x4 h0, h1;
#pragma unroll
            for (int r = 0; r < 4; ++r) {
                h0[r] = (_Float16)fmaxf(c0[r], 0.f);
                h1[r] = (_Float16)fmaxf(c1[r], 0.f);
            }
            *(f16x4*)&lds[(rowv + n16) * S + quad * 4]      = h0;
            *(f16x4*)&lds[(rowv + n16) * S + 16 + quad * 4] = h1;
        }
    }
    LDS_FENCE();

    // ========== Phase 3: G2 (32->64), H1 -> H2, in place ==========
    {
        f16x8 w[4];
#pragma unroll
        for (int q = 0; q < 4; ++q) w[q] = frag(2 + q);
#pragma unroll
        for (int g = 0; g < 4; ++g) {
            const int rowv = (g0 + g) * 16;
            const f16x8 a = *(const f16x8*)&lds[(rowv + n16) * S + quad * 8];
            f32x4 c[4];
#pragma unroll
            for (int q = 0; q < 4; ++q) {
                c[q] = (f32x4){0.f, 0.f, 0.f, 0.f};
                c[q] = __builtin_amdgcn_mfma_f32_16x16x32_f16(w[q], a, c[q], 0, 0, 0);
            }
#pragma unroll
            for (int q = 0; q < 4; ++q) {
                f16x4 h;
#pragma unroll
                for (int r = 0; r < 4; ++r) h[r] = (_Float16)fmaxf(c[q][r], 0.f);
                *(f16x4*)&lds[(rowv + n16) * S + q * 16 + quad * 4] = h;
            }
        }
    }
    LDS_FENCE();

    // ========== Phase 4: G3 (64->32), H2 -> F (f32, no relu), in place ==========
    {
        const f16x8 w00 = frag(6), w01 = frag(7), w10 = frag(8), w11 = frag(9);
#pragma unroll
        for (int g = 0; g < 4; ++g) {
            const int rowv = (g0 + g) * 16;
            const f16x8 a0 = *(const f16x8*)&lds[(rowv + n16) * S + quad * 8];
            const f16x8 a1 = *(const f16x8*)&lds[(rowv + n16) * S + 32 + quad * 8];
            f32x4 c0 = {0.f, 0.f, 0.f, 0.f}, c1 = {0.f, 0.f, 0.f, 0.f};
            c0 = __builtin_amdgcn_mfma_f32_16x16x32_f16(w00, a0, c0, 0, 0, 0);
            c0 = __builtin_amdgcn_mfma_f32_16x16x32_f16(w10, a1, c0, 0, 0, 0);
            c1 = __builtin_amdgcn_mfma_f32_16x16x32_f16(w01, a0, c1, 0, 0, 0);
            c1 = __builtin_amdgcn_mfma_f32_16x16x32_f16(w11, a1, c1, 0, 0, 0);
            // channels [quad*4, +4) and [16+quad*4, +4) of voxel rowv+n16, f32
            *(f32x4*)&ldsf[(rowv + n16) * SD + quad * 4]      = c0;
            *(f32x4*)&ldsf[(rowv + n16) * SD + 16 + quad * 4] = c1;
        }
    }
    LDS_FENCE();

    // ========== Phase 5: out = (x . F) * 2^-14, x already in registers ==========
    {
        float s0 = 0.f, s1 = 0.f, s2 = 0.f, s3 = 0.f;   // 4 chains, not 1x32
#pragma unroll
        for (int i = 0; i < 8; ++i) {
            const f32x4 f = *(const f32x4*)&ldsf[t * SD + i * 4];
            s0 = fmaf(xv[i * 4 + 0], f[0], s0);
            s1 = fmaf(xv[i * 4 + 1], f[1], s1);
            s2 = fmaf(xv[i * 4 + 2], f[2], s2);
            s3 = fmaf(xv[i * 4 + 3], f[3], s3);
        }
        out[b * V3 + v] = ((s0 + s1) + (s2 + s3)) * INV_SCALE;
    }
}

extern "C" void kernel_launch(void* const* d_in, const int* in_sizes, int n_in,
                              void* d_out, int out_size, void* d_ws, size_t ws_size,
                              hipStream_t stream) {
    const float* x     = (const float*)d_in[0];
    const float* d_all = (const float*)d_in[1];
    const float* W1    = (const float*)d_in[2];
    const float* W2    = (const float*)d_in[3];
    const float* G1    = (const float*)d_in[4];
    const float* G2    = (const float*)d_in[5];
    const float* G3    = (const float*)d_in[6];
    float* out = (float*)d_out;

    if (ws_size >= (size_t)WS_BYTES) {
        _Float16* wf = (_Float16*)d_ws;
        pack_weights<<<1, 256, 0, stream>>>(G1, G2, G3, wf);
        metaclf_mfma3<true><<<NBLK, 256, 0, stream>>>(
            x, d_all, W1, W2, G1, G2, G3, wf, out);
    } else {
        metaclf_mfma3<false><<<NBLK, 256, 0, stream>>>(
            x, d_all, W1, W2, G1, G2, G3, nullptr, out);
    }
}